// Round 7
// baseline (89.207 us; speedup 1.0000x reference)
//
#include <hip/hip_runtime.h>
#include <float.h>

#define POOL 7
#define FW 2048
#define FH 2048

// One block per box, NO window staging.
// 196 lanes = 4 row-split slots x 49 spatial outputs; each lane reads its bin
// directly from global as 5 predicated float4 groups per row, BOTH channels
// issued together (10 loads in flight, one wait per row-iter, <=4 row-iters).
// Column masks are loop-invariant (hoisted v_cmp). Bin overlap (<=1 row/col
// between neighboring bins) hits L1/L2. Only LDS: pooled[98] + delta[4].
// Overreads: col offset <= x1a+103 -> wraps into adjacent rows of the same
// in-bounds allocation (y1+95 <= 2046), values masked to -FLT_MAX.
__global__ __launch_bounds__(256, 4) void roi_pool_fc_kernel(
    const float* __restrict__ feature,   // [2, 2048, 2048]
    const float* __restrict__ boxes,     // [N, 6]
    const int*   __restrict__ coords,    // [N, 4] (y1, x1, y2, x2)
    const float* __restrict__ fc_w,      // [4, 98]
    const float* __restrict__ fc_b,      // [4]
    float* __restrict__ out,             // [N, 6]
    int N)
{
    const int n = blockIdx.x;
    const int t = threadIdx.x;

    __shared__ float pooled[98];   // channel-major: c*49 + i*7 + j
    __shared__ float delta[4];

    const int4 cd = ((const int4*)coords)[n];   // uniform -> s_load
    const int y1 = cd.x;
    const int x1 = cd.y;
    const int h  = cd.z - y1;   // 7 <= h <= 96
    const int w  = cd.w - x1;   // 7 <= w <= 96

    const int x1a = x1 & ~3;    // 16B-aligned
    const int off = x1 - x1a;   // 0..3

    // FC prefetch (hidden under binmax loads)
    float wpre[4] = {0.f, 0.f, 0.f, 0.f};
    float bias = 0.f;
    if (t < 128) {
        const int oo = t >> 5, lane = t & 31;
        const float* wrow = fc_w + oo * 98;
        #pragma unroll
        for (int k = 0; k < 4; ++k) {
            const int idx = lane + 32 * k;
            if (idx < 98) wpre[k] = wrow[idx];
        }
        if (lane == 0) bias = fc_b[oo];
    }
    const float bx = (t < 6) ? boxes[n * 6 + t] : 0.f;

    if (t < 196) {
        const int o = t >> 2;        // spatial output 0..48
        const int s = t & 3;         // row-split slot
        const int i = o / 7;
        const int j = o % 7;
        // PyTorch adaptive bins
        const int sr  = (i * h) / POOL;
        const int er  = ((i + 1) * h + POOL - 1) / POOL;        // er <= h <= 96
        const int sc  = (j * w) / POOL + off;
        const int ec  = ((j + 1) * w + POOL - 1) / POOL + off;  // ec - sc <= 14
        const int sc4 = sc >> 2;                                // needed groups fit in [sc4, sc4+5)

        const float* r0 = feature + (size_t)y1 * FW + x1a + 4 * sc4;   // ch0 bin base
        const float* r1 = r0 + (size_t)FH * FW;                        // ch1 bin base

        float m0 = -FLT_MAX, m1 = -FLT_MAX;
        for (int r = sr + s; r < er; r += 4) {                  // <= 4 iters
            const float4* p0 = (const float4*)(r0 + (size_t)r * FW);
            const float4* p1 = (const float4*)(r1 + (size_t)r * FW);
            float4 v0[5], v1[5];
            #pragma unroll
            for (int q = 0; q < 5; ++q) { v0[q] = p0[q]; v1[q] = p1[q]; }
            #pragma unroll
            for (int q = 0; q < 5; ++q) {
                const int b = (sc4 + q) * 4;
                const bool e0 = (b + 0 >= sc) & (b + 0 < ec);   // loop-invariant
                const bool e1 = (b + 1 >= sc) & (b + 1 < ec);
                const bool e2 = (b + 2 >= sc) & (b + 2 < ec);
                const bool e3 = (b + 3 >= sc) & (b + 3 < ec);
                m0 = fmaxf(m0, e0 ? v0[q].x : -FLT_MAX);
                m0 = fmaxf(m0, e1 ? v0[q].y : -FLT_MAX);
                m0 = fmaxf(m0, e2 ? v0[q].z : -FLT_MAX);
                m0 = fmaxf(m0, e3 ? v0[q].w : -FLT_MAX);
                m1 = fmaxf(m1, e0 ? v1[q].x : -FLT_MAX);
                m1 = fmaxf(m1, e1 ? v1[q].y : -FLT_MAX);
                m1 = fmaxf(m1, e2 ? v1[q].z : -FLT_MAX);
                m1 = fmaxf(m1, e3 ? v1[q].w : -FLT_MAX);
            }
        }
        // combine 4 row-split lanes (same wave, lanes o*4..o*4+3)
        m0 = fmaxf(m0, __shfl_xor(m0, 1, 64));
        m0 = fmaxf(m0, __shfl_xor(m0, 2, 64));
        m1 = fmaxf(m1, __shfl_xor(m1, 1, 64));
        m1 = fmaxf(m1, __shfl_xor(m1, 2, 64));
        if (s == 0) { pooled[o] = m0; pooled[49 + o] = m1; }
    }
    __syncthreads();

    // FC (98 -> 4), 32 lanes per output, prefetched weights
    if (t < 128) {
        const int lane = t & 31;
        float acc = 0.f;
        #pragma unroll
        for (int k = 0; k < 4; ++k) {
            const int idx = lane + 32 * k;
            acc = fmaf(idx < 98 ? pooled[idx] : 0.f, wpre[k], acc);
        }
        #pragma unroll
        for (int mm = 16; mm; mm >>= 1)
            acc += __shfl_xor(acc, mm, 64);   // masks <32 stay within 32-lane group
        if (lane == 0) delta[t >> 5] = fmaxf(acc + bias, 0.f);
    }
    __syncthreads();

    if (t < 6)
        out[n * 6 + t] = bx + (t >= 2 ? delta[t - 2] : 0.f);
}

extern "C" void kernel_launch(void* const* d_in, const int* in_sizes, int n_in,
                              void* d_out, int out_size, void* d_ws, size_t ws_size,
                              hipStream_t stream) {
    const float* feature = (const float*)d_in[0];  // [1,2,2048,2048] fp32
    const float* boxes   = (const float*)d_in[1];  // [N,6] fp32
    const int*   coords  = (const int*)d_in[2];    // [N,4] int32
    const float* fc_w    = (const float*)d_in[3];  // [4,98] fp32
    const float* fc_b    = (const float*)d_in[4];  // [4] fp32
    float* out = (float*)d_out;                    // [N,6] fp32

    const int N = in_sizes[2] / 4;
    roi_pool_fc_kernel<<<N, 256, 0, stream>>>(feature, boxes, coords, fc_w, fc_b, out, N);
}